// Round 1
// baseline (40931.885 us; speedup 1.0000x reference)
//
#include <hip/hip_runtime.h>

// Program-guided CNN executor, fp32 VALU implementation.
// B=32, T=30, C=128, 14x14 spatial, P=196 positions per channel.
// Scan step = 3 conv stages (separate launches = grid barrier).
// Binary 256-ch conv1 split into two 128-ch partial convs (h1a,h1b),
// relu(h1a+h1b) fused into stage-2 LDS staging.

#define NSTEP 30
#define CD 147456            // 128*128*9 = CONV_DIM
#define P 196
#define FSZ 25088            // 128*196 floats per (b, buffer)

__constant__ int KIND_TBL[44] = {
  0,0,0,0,1,3,3,3,3,3,
  2,2,2,2,2,2,2,2,2,2,
  2,2,2,2,2,2,3,3,3,2,
  2,2,2,2,2,2,2,2,2,2,
  2,2,3,2};
__constant__ int MIDX_TBL[44] = {
  0,0,0,0,0,0,1,2,3,4,
  1,2,3,4,5,6,7,8,9,10,
  11,12,13,14,15,16,5,6,7,17,
  18,19,20,21,22,23,24,25,26,27,
  28,29,8,30};

// One WG: 16 out-channels x all 196 positions. Threads = padded 16x16 plane.
// Weights: uniform addresses -> scalar loads (scalar pipe, SGPR FMA operand).
__device__ __forceinline__ void conv_core(
    const float* __restrict__ in1, const float* __restrict__ in2, // in2: staged val = relu(in1+in2)
    const float* __restrict__ W, int wic, int nic,
    const float* __restrict__ bias, int oc0,
    float* __restrict__ dst, float* __restrict__ dst2, float* __restrict__ zbuf,
    bool dorelu)
{
  __shared__ float s_in[8 * 256];
  const int tid = threadIdx.x;
  const int r = tid >> 4, cc = tid & 15;
  // LDS plane holds rows/cols [-1..14] of the 14x14 image (halo), exactly 16x16.
  const bool ldv = (r >= 1) && (r <= 14) && (cc >= 1) && (cc <= 14);
  const int lidx = ldv ? ((r - 1) * 14 + (cc - 1)) : 0;
  const bool active = (r < 14) && (cc < 14);
  float acc[16];
#pragma unroll
  for (int j = 0; j < 16; ++j) acc[j] = 0.f;

  for (int c0 = 0; c0 < nic; c0 += 8) {
    __syncthreads();
#pragma unroll
    for (int c = 0; c < 8; ++c) {
      float v = 0.f;
      if (ldv) {
        v = in1[(size_t)(c0 + c) * P + lidx];
        if (in2) v = fmaxf(v + in2[(size_t)(c0 + c) * P + lidx], 0.f);
      }
      s_in[c * 256 + tid] = v;
    }
    __syncthreads();
    if (active) {
#pragma unroll
      for (int c = 0; c < 8; ++c) {
        float xv[9];
#pragma unroll
        for (int dy = 0; dy < 3; ++dy)
#pragma unroll
          for (int dx = 0; dx < 3; ++dx)
            xv[dy * 3 + dx] = s_in[c * 256 + (r + dy) * 16 + (cc + dx)];
        const size_t kbase = (size_t)(c0 + c) * 9;
#pragma unroll
        for (int j = 0; j < 16; ++j) {
          const float* wr = W + (size_t)(oc0 + j) * wic * 9 + kbase; // uniform -> s_load
#pragma unroll
          for (int t = 0; t < 9; ++t)
            acc[j] = fmaf(wr[t], xv[t], acc[j]);
        }
      }
    }
  }
  if (active) {
    const int pidx = r * 14 + cc;
#pragma unroll
    for (int j = 0; j < 16; ++j) {
      float v = acc[j];
      if (bias) v += bias[oc0 + j];
      if (dorelu) v = fmaxf(v, 0.f);
      dst[(size_t)(oc0 + j) * P + pidx] = v;
      if (dst2) dst2[(size_t)(oc0 + j) * P + pidx] = v;
      if (zbuf) zbuf[(size_t)(oc0 + j) * P + pidx] = 0.f; // zero-init of `saved`
    }
  }
}

__global__ void __launch_bounds__(256) stem1_kernel(
    const float* __restrict__ feats, const float* __restrict__ w,
    const float* __restrict__ b, float* __restrict__ dst)
{
  const int bb = blockIdx.y;
  conv_core(feats + (size_t)bb * 1024 * P, nullptr, w, 1024, 1024, b,
            blockIdx.x * 16, dst + (size_t)bb * FSZ, nullptr, nullptr, true);
}

__global__ void __launch_bounds__(256) stem2_kernel(
    const float* __restrict__ hin, const float* __restrict__ w,
    const float* __restrict__ b, float* __restrict__ feat,
    float* __restrict__ outb, float* __restrict__ saved)
{
  const int bb = blockIdx.y;
  const size_t bo = (size_t)bb * FSZ;
  // writes feat AND out (scan carry init = feat), zeroes saved.
  conv_core(hin + bo, nullptr, w, 128, 128, b, blockIdx.x * 16,
            feat + bo, outb + bo, saved + bo, true);
}

__global__ void __launch_bounds__(256) step_kernel(
    int stage, int s, const int* __restrict__ progs,
    const float* __restrict__ mem_u, const float* __restrict__ mem_b,
    const float* __restrict__ feat, float* __restrict__ outb,
    float* __restrict__ saved, float* __restrict__ h1a,
    float* __restrict__ h1b, float* __restrict__ h2)
{
  const int bb = blockIdx.y;
  const int ocb = blockIdx.x;
  int tok = progs[bb * NSTEP + (NSTEP - 1 - s)];      // scan runs program reversed
  tok = __builtin_amdgcn_readfirstlane(tok);          // force uniform -> scalar weight addressing
  const int kind = KIND_TBL[tok];
  if (kind == 0) return;
  const int mi = MIDX_TBL[tok];
  const size_t bo = (size_t)bb * FSZ;
  const float *in1 = nullptr, *in2 = nullptr, *W = nullptr;
  float* dst = nullptr;
  int wic = 128, oc0 = ocb * 16;
  bool rl = true;

  if (stage == 1) {
    if (kind == 1) {          // scene: conv1(feat) in WGs 0..7; saved<-out copy in WGs 8..15
      if (ocb >= 8) {
        const size_t ch0 = bo + (size_t)(ocb - 8) * 16 * P;
        for (int i = threadIdx.x; i < 16 * P; i += 256) saved[ch0 + i] = outb[ch0 + i];
        return;
      }
      in1 = feat + bo; W = mem_u; dst = h1a + bo;
    } else if (kind == 2) {   // unary conv1
      if (ocb >= 8) return;
      in1 = outb + bo; W = mem_u + (size_t)mi * 2 * CD; dst = h1a + bo;
    } else {                  // binary conv1, split: out-part (ic 0..127) / saved-part (ic 128..255)
      const float* Wb = mem_b + (size_t)mi * 4 * CD;
      wic = 256; rl = false;  // no relu: sum happens in stage 2 staging
      if (ocb < 8) { in1 = outb + bo;  W = Wb;            dst = h1a + bo; }
      else         { in1 = saved + bo; W = Wb + 128 * 9;  dst = h1b + bo; oc0 = (ocb - 8) * 16; }
    }
  } else if (stage == 2) {
    if (kind == 1)      { in1 = h1a + bo; W = mem_u + CD;                          dst = outb + bo; }
    else if (kind == 2) { in1 = h1a + bo; W = mem_u + (size_t)mi * 2 * CD + CD;    dst = outb + bo; }
    else { in1 = h1a + bo; in2 = h1b + bo;                                         // relu(h1a+h1b) fused
           W = mem_b + (size_t)mi * 4 * CD + 2 * (size_t)CD;                       dst = h2 + bo; }
  } else {
    if (kind != 3) return;
    in1 = h2 + bo; W = mem_b + (size_t)mi * 4 * CD + 3 * (size_t)CD; dst = outb + bo;
  }
  conv_core(in1, in2, W, wic, 128, nullptr, oc0, dst, nullptr, nullptr, rl);
}

// conv1x1(128->512)+bias+relu+2x2 maxpool, writes hB[b][oc*49+pp] (b-major, coalesced).
__global__ void __launch_bounds__(256) cls_pool_kernel(
    const float* __restrict__ x, const float* __restrict__ Wc,
    const float* __restrict__ bc, float* __restrict__ hB)
{
  const int b = blockIdx.y, og = blockIdx.x;   // og: 64 out-channels
  const int oc0 = og * 64;
  __shared__ float s[16 * P];
  const float* xb = x + (size_t)b * FSZ;
  const int tid = threadIdx.x;
  float acc[13][4];
#pragma unroll
  for (int k = 0; k < 13; ++k) { acc[k][0] = acc[k][1] = acc[k][2] = acc[k][3] = 0.f; }

  for (int c0 = 0; c0 < 128; c0 += 16) {
    __syncthreads();
    for (int i = tid; i < 16 * P; i += 256) s[i] = xb[(size_t)c0 * P + i];
    __syncthreads();
#pragma unroll
    for (int k = 0; k < 13; ++k) {
      const int idx = k * 256 + tid;
      if (idx < 64 * 49) {
        const int oc = oc0 + idx / 49, pp = idx % 49;
        const int py = pp / 7, px = pp % 7;
        const int b0 = 2 * py * 14 + 2 * px, b1 = b0 + 14;
        const float* wr = Wc + (size_t)oc * 128 + c0;
#pragma unroll
        for (int ic = 0; ic < 16; ++ic) {
          const float w = wr[ic];
          const float* sp = s + ic * P;
          const float2 r0 = *(const float2*)(sp + b0);
          const float2 r1 = *(const float2*)(sp + b1);
          acc[k][0] = fmaf(w, r0.x, acc[k][0]);
          acc[k][1] = fmaf(w, r0.y, acc[k][1]);
          acc[k][2] = fmaf(w, r1.x, acc[k][2]);
          acc[k][3] = fmaf(w, r1.y, acc[k][3]);
        }
      }
    }
  }
#pragma unroll
  for (int k = 0; k < 13; ++k) {
    const int idx = k * 256 + tid;
    if (idx < 64 * 49) {
      const int oc = oc0 + idx / 49, pp = idx % 49;
      const float m = fmaxf(fmaxf(acc[k][0], acc[k][1]), fmaxf(acc[k][2], acc[k][3]));
      hB[(size_t)b * 25088 + (size_t)oc * 49 + pp] = fmaxf(m + bc[oc], 0.f); // max-then-relu == relu-then-max
    }
  }
}

// hB[b][k] -> hT[k][b] so fc1 reads are lane-coalesced over b.
__global__ void __launch_bounds__(256) transpose_kernel(
    const float* __restrict__ hB, float* __restrict__ hT)
{
  __shared__ float t[256 * 33];
  const int k0 = blockIdx.x * 256;
  const int tid = threadIdx.x;
  for (int b = 0; b < 32; ++b)
    t[tid * 33 + b] = hB[(size_t)b * 25088 + k0 + tid];
  __syncthreads();
  for (int i = tid; i < 256 * 32; i += 256) {
    const int k = i >> 5, b = i & 31;
    hT[(size_t)(k0 + k) * 32 + b] = t[k * 33 + b];
  }
}

__global__ void __launch_bounds__(256) fc1_kernel(
    const float* __restrict__ hT, const float* __restrict__ W,
    const float* __restrict__ bias, float* __restrict__ o)
{
  const int b = threadIdx.x & 31, j = threadIdx.x >> 5;
  const int oc = blockIdx.x * 8 + j;
  const float* wr = W + (size_t)oc * 25088;
  float acc = 0.f;
  for (int k = 0; k < 25088; k += 4) {
    const float4 w4 = *(const float4*)(wr + k);
    acc = fmaf(hT[(size_t)(k + 0) * 32 + b], w4.x, acc);
    acc = fmaf(hT[(size_t)(k + 1) * 32 + b], w4.y, acc);
    acc = fmaf(hT[(size_t)(k + 2) * 32 + b], w4.z, acc);
    acc = fmaf(hT[(size_t)(k + 3) * 32 + b], w4.w, acc);
  }
  o[(size_t)b * 1024 + oc] = fmaxf(acc + bias[oc], 0.f);
}

__global__ void __launch_bounds__(256) fc2_kernel(
    const float* __restrict__ h, const float* __restrict__ W,
    const float* __restrict__ bias, float* __restrict__ out)
{
  const int i = blockIdx.x * 256 + threadIdx.x;
  const int b = i >> 5, oo = i & 31;
  const float* wr = W + (size_t)oo * 1024;
  const float* hr = h + (size_t)b * 1024;
  float acc = bias[oo];
  for (int k = 0; k < 1024; k += 4) {
    const float4 w4 = *(const float4*)(wr + k);
    const float4 h4 = *(const float4*)(hr + k);
    acc = fmaf(h4.x, w4.x, acc);
    acc = fmaf(h4.y, w4.y, acc);
    acc = fmaf(h4.z, w4.z, acc);
    acc = fmaf(h4.w, w4.w, acc);
  }
  out[i] = acc;
}

extern "C" void kernel_launch(void* const* d_in, const int* in_sizes, int n_in,
                              void* d_out, int out_size, void* d_ws, size_t ws_size,
                              hipStream_t stream) {
  const float* feats   = (const float*)d_in[0];
  const int*   progs   = (const int*)  d_in[1];
  const float* stem_w1 = (const float*)d_in[2];
  const float* stem_b1 = (const float*)d_in[3];
  const float* stem_w2 = (const float*)d_in[4];
  const float* stem_b2 = (const float*)d_in[5];
  const float* mem_u   = (const float*)d_in[6];
  const float* mem_b   = (const float*)d_in[7];
  const float* cls_w   = (const float*)d_in[8];
  const float* cls_b   = (const float*)d_in[9];
  const float* fc1_w   = (const float*)d_in[10];
  const float* fc1_b   = (const float*)d_in[11];
  const float* fc2_w   = (const float*)d_in[12];
  const float* fc2_b   = (const float*)d_in[13];

  float* ws = (float*)d_ws;
  const size_t F = (size_t)32 * FSZ;   // 802816 floats per activation buffer
  float* feat  = ws;
  float* outb  = ws + 1 * F;
  float* saved = ws + 2 * F;
  float* h1a   = ws + 3 * F;
  float* h1b   = ws + 4 * F;
  float* h2    = ws + 5 * F;
  float* hT    = ws + 6 * F;
  float* fc1o  = ws + 7 * F;           // 32768 floats used

  const dim3 blk(256);
  stem1_kernel<<<dim3(8, 32), blk, 0, stream>>>(feats, stem_w1, stem_b1, h1a);
  stem2_kernel<<<dim3(8, 32), blk, 0, stream>>>(h1a, stem_w2, stem_b2, feat, outb, saved);

  for (int s = 0; s < NSTEP; ++s) {
    step_kernel<<<dim3(16, 32), blk, 0, stream>>>(1, s, progs, mem_u, mem_b, feat, outb, saved, h1a, h1b, h2);
    step_kernel<<<dim3(8, 32),  blk, 0, stream>>>(2, s, progs, mem_u, mem_b, feat, outb, saved, h1a, h1b, h2);
    step_kernel<<<dim3(8, 32),  blk, 0, stream>>>(3, s, progs, mem_u, mem_b, feat, outb, saved, h1a, h1b, h2);
  }

  float* hB = h1a; // reuse
  cls_pool_kernel<<<dim3(8, 32), blk, 0, stream>>>(outb, cls_w, cls_b, hB);
  transpose_kernel<<<dim3(98), blk, 0, stream>>>(hB, hT);
  fc1_kernel<<<dim3(128), blk, 0, stream>>>(hT, fc1_w, fc1_b, fc1o);
  fc2_kernel<<<dim3(4), blk, 0, stream>>>(fc1o, fc2_w, fc2_b, (float*)d_out);
}

// Round 2
// 15366.370 us; speedup vs baseline: 2.6637x; 2.6637x over previous
//
#include <hip/hip_runtime.h>

// Program-guided CNN executor, fp32 VALU, persistent-kernel version.
// B=32, T=30, C=128, 14x14 spatial (P=196).
// One persistent kernel runs stem + all 30 scan steps. 512 WGs = 32 b x 16
// slices (8 oc each). Stages within a batch element are ordered by per-b
// atomic barriers (16 arrivals, agent scope); different b's pipeline freely.

#define NSTEP 30
#define CD 147456            // 128*128*9
#define P 196
#define FSZ 25088            // 128*196 floats per (b, buffer)

__constant__ int KIND_TBL[44] = {
  0,0,0,0,1,3,3,3,3,3,
  2,2,2,2,2,2,2,2,2,2,
  2,2,2,2,2,2,3,3,3,2,
  2,2,2,2,2,2,2,2,2,2,
  2,2,3,2};
__constant__ int MIDX_TBL[44] = {
  0,0,0,0,0,0,1,2,3,4,
  1,2,3,4,5,6,7,8,9,10,
  11,12,13,14,15,16,5,6,7,17,
  18,19,20,21,22,23,24,25,26,27,
  28,29,8,30};

// Per-b barrier among the 16 WGs of one batch element. Monotone counter:
// WGs arrive with release-add, spin until cumulative count reaches 16*phase.
__device__ __forceinline__ void bbar(int* __restrict__ ctr, int target) {
  __syncthreads();
  if (threadIdx.x == 0) {
    __hip_atomic_fetch_add(ctr, 1, __ATOMIC_RELEASE, __HIP_MEMORY_SCOPE_AGENT);
    while (__hip_atomic_load(ctr, __ATOMIC_ACQUIRE, __HIP_MEMORY_SCOPE_AGENT) < target)
      __builtin_amdgcn_s_sleep(2);
  }
  __syncthreads();
}

// 8 out-channels x 196 positions conv3x3. Threads = padded 16x16 halo plane.
// Input channel c reads in_a while c < ic_split, else in_b (binary concat).
// W is pre-offset to this WG's first oc row; wrow = nic*9 row stride.
// dst/dst2/zb pre-offset to this WG's first channel. Weight addresses are
// wave-uniform -> scalar loads on the scalar pipe.
__device__ __forceinline__ void conv8(
    const float* __restrict__ in_a, const float* __restrict__ in_b,
    int ic_split, int nic,
    const float* __restrict__ W, int wrow,
    const float* __restrict__ bias,
    float* __restrict__ dst, float* __restrict__ dst2, float* __restrict__ zb,
    float* __restrict__ s_in)
{
  const int tid = threadIdx.x;
  const int r = tid >> 4, cc = tid & 15;
  const bool ldv = (r >= 1) && (r <= 14) && (cc >= 1) && (cc <= 14);
  const int lidx = ldv ? ((r - 1) * 14 + (cc - 1)) : 0;
  const bool active = (r < 14) && (cc < 14);
  float acc[8];
#pragma unroll
  for (int j = 0; j < 8; ++j) acc[j] = 0.f;

  for (int c0 = 0; c0 < nic; c0 += 8) {
    const float* src = (c0 < ic_split) ? (in_a + (size_t)c0 * P)
                                       : (in_b + (size_t)(c0 - ic_split) * P);
    __syncthreads();
#pragma unroll
    for (int c = 0; c < 8; ++c)
      s_in[c * 256 + tid] = ldv ? src[(size_t)c * P + lidx] : 0.f;
    __syncthreads();
    if (active) {
      const float* wc = W + (size_t)c0 * 9;
#pragma unroll
      for (int c = 0; c < 8; ++c) {
        float xv[9];
#pragma unroll
        for (int dy = 0; dy < 3; ++dy)
#pragma unroll
          for (int dx = 0; dx < 3; ++dx)
            xv[dy * 3 + dx] = s_in[c * 256 + (r + dy) * 16 + (cc + dx)];
#pragma unroll
        for (int j = 0; j < 8; ++j) {
          const float* w9 = wc + (size_t)j * wrow + c * 9;   // uniform -> s_load
#pragma unroll
          for (int t = 0; t < 9; ++t)
            acc[j] = fmaf(w9[t], xv[t], acc[j]);
        }
      }
    }
  }
  if (active) {
    const int pidx = r * 14 + cc;
#pragma unroll
    for (int j = 0; j < 8; ++j) {
      float v = acc[j];
      if (bias) v += bias[j];
      v = fmaxf(v, 0.f);
      dst[(size_t)j * P + pidx] = v;
      if (dst2) dst2[(size_t)j * P + pidx] = v;
      if (zb)   zb[(size_t)j * P + pidx] = 0.f;
    }
  }
}

__global__ void __launch_bounds__(256, 2) persist_kernel(
    const float* __restrict__ feats, const int* __restrict__ progs,
    const float* __restrict__ sw1, const float* __restrict__ sb1,
    const float* __restrict__ sw2, const float* __restrict__ sb2,
    const float* __restrict__ mem_u, const float* __restrict__ mem_b,
    float* __restrict__ feat, float* __restrict__ outb,
    float* __restrict__ saved, float* __restrict__ h1,
    float* __restrict__ h2, int* __restrict__ ctr)
{
  __shared__ float s_in[8 * 256];
  const int wg = blockIdx.x;
  const int b = wg >> 4;           // batch element
  const int oc0 = (wg & 15) * 8;   // this WG's out-channel slice
  const size_t bo = (size_t)b * FSZ;
  const size_t co = bo + (size_t)oc0 * P;
  int* myctr = ctr + b * 32;       // one cache line per b
  int phase = 0;

  // stem1: feats (1024 ic) -> h1
  conv8(feats + (size_t)b * 1024 * P, nullptr, 1 << 30, 1024,
        sw1 + (size_t)oc0 * 1024 * 9, 1024 * 9, sb1 + oc0,
        h1 + co, nullptr, nullptr, s_in);
  bbar(myctr, ++phase * 16);
  // stem2: h1 -> feat; also init scan carry: outb = feat, saved = 0
  conv8(h1 + bo, nullptr, 1 << 30, 128,
        sw2 + (size_t)oc0 * 128 * 9, 128 * 9, sb2 + oc0,
        feat + co, outb + co, saved + co, s_in);
  bbar(myctr, ++phase * 16);

  for (int s = 0; s < NSTEP; ++s) {
    int tok = __builtin_amdgcn_readfirstlane(progs[b * NSTEP + (NSTEP - 1 - s)]);
    const int kind = KIND_TBL[tok];
    if (kind == 0) continue;                      // noop: no barriers, uniform per b
    const int mi = MIDX_TBL[tok];
    if (kind == 3) {                              // binary: 3 convs, conv1 has 256 ic
      const float* Wb = mem_b + (size_t)mi * 4 * CD;
      conv8(outb + bo, saved + bo, 128, 256,
            Wb + (size_t)oc0 * 2304, 2304, nullptr,
            h1 + co, nullptr, nullptr, s_in);
      bbar(myctr, ++phase * 16);
      conv8(h1 + bo, nullptr, 1 << 30, 128,
            Wb + 2 * (size_t)CD + (size_t)oc0 * 1152, 1152, nullptr,
            h2 + co, nullptr, nullptr, s_in);
      bbar(myctr, ++phase * 16);
      conv8(h2 + bo, nullptr, 1 << 30, 128,
            Wb + 3 * (size_t)CD + (size_t)oc0 * 1152, 1152, nullptr,
            outb + co, nullptr, nullptr, s_in);
      bbar(myctr, ++phase * 16);
    } else {                                      // unary (kind 2) / scene (kind 1)
      const float* Wu = mem_u + (kind == 1 ? 0 : (size_t)mi * 2 * (size_t)CD);
      if (kind == 1) {
        // new_saved = old out: copy my 8 channels (conv below reads feat, not outb)
        for (int i = threadIdx.x; i < 8 * P; i += 256)
          saved[co + i] = outb[co + i];
      }
      conv8((kind == 1 ? feat : outb) + bo, nullptr, 1 << 30, 128,
            Wu + (size_t)oc0 * 1152, 1152, nullptr,
            h1 + co, nullptr, nullptr, s_in);
      bbar(myctr, ++phase * 16);
      conv8(h1 + bo, nullptr, 1 << 30, 128,
            Wu + CD + (size_t)oc0 * 1152, 1152, nullptr,
            outb + co, nullptr, nullptr, s_in);
      bbar(myctr, ++phase * 16);
    }
  }
}

// conv1x1(128->512)+bias+relu+2x2 maxpool, writes hB[b][oc*49+pp].
__global__ void __launch_bounds__(256) cls_pool_kernel(
    const float* __restrict__ x, const float* __restrict__ Wc,
    const float* __restrict__ bc, float* __restrict__ hB)
{
  const int b = blockIdx.y, og = blockIdx.x;
  const int oc0 = og * 64;
  __shared__ float s[16 * P];
  const float* xb = x + (size_t)b * FSZ;
  const int tid = threadIdx.x;
  float acc[13][4];
#pragma unroll
  for (int k = 0; k < 13; ++k) { acc[k][0] = acc[k][1] = acc[k][2] = acc[k][3] = 0.f; }

  for (int c0 = 0; c0 < 128; c0 += 16) {
    __syncthreads();
    for (int i = tid; i < 16 * P; i += 256) s[i] = xb[(size_t)c0 * P + i];
    __syncthreads();
#pragma unroll
    for (int k = 0; k < 13; ++k) {
      const int idx = k * 256 + tid;
      if (idx < 64 * 49) {
        const int oc = oc0 + idx / 49, pp = idx % 49;
        const int py = pp / 7, px = pp % 7;
        const int b0 = 2 * py * 14 + 2 * px, b1 = b0 + 14;
        const float* wr = Wc + (size_t)oc * 128 + c0;
#pragma unroll
        for (int ic = 0; ic < 16; ++ic) {
          const float w = wr[ic];
          const float* sp = s + ic * P;
          const float2 r0 = *(const float2*)(sp + b0);
          const float2 r1 = *(const float2*)(sp + b1);
          acc[k][0] = fmaf(w, r0.x, acc[k][0]);
          acc[k][1] = fmaf(w, r0.y, acc[k][1]);
          acc[k][2] = fmaf(w, r1.x, acc[k][2]);
          acc[k][3] = fmaf(w, r1.y, acc[k][3]);
        }
      }
    }
  }
#pragma unroll
  for (int k = 0; k < 13; ++k) {
    const int idx = k * 256 + tid;
    if (idx < 64 * 49) {
      const int oc = oc0 + idx / 49, pp = idx % 49;
      const float m = fmaxf(fmaxf(acc[k][0], acc[k][1]), fmaxf(acc[k][2], acc[k][3]));
      hB[(size_t)b * 25088 + (size_t)oc * 49 + pp] = fmaxf(m + bc[oc], 0.f);
    }
  }
}

__global__ void __launch_bounds__(256) transpose_kernel(
    const float* __restrict__ hB, float* __restrict__ hT)
{
  __shared__ float t[256 * 33];
  const int k0 = blockIdx.x * 256;
  const int tid = threadIdx.x;
  for (int b = 0; b < 32; ++b)
    t[tid * 33 + b] = hB[(size_t)b * 25088 + k0 + tid];
  __syncthreads();
  for (int i = tid; i < 256 * 32; i += 256) {
    const int k = i >> 5, b = i & 31;
    hT[(size_t)(k0 + k) * 32 + b] = t[k * 33 + b];
  }
}

__global__ void __launch_bounds__(256) fc1_kernel(
    const float* __restrict__ hT, const float* __restrict__ W,
    const float* __restrict__ bias, float* __restrict__ o)
{
  const int b = threadIdx.x & 31, j = threadIdx.x >> 5;
  const int oc = blockIdx.x * 8 + j;
  const float* wr = W + (size_t)oc * 25088;
  float acc = 0.f;
  for (int k = 0; k < 25088; k += 4) {
    const float4 w4 = *(const float4*)(wr + k);
    acc = fmaf(hT[(size_t)(k + 0) * 32 + b], w4.x, acc);
    acc = fmaf(hT[(size_t)(k + 1) * 32 + b], w4.y, acc);
    acc = fmaf(hT[(size_t)(k + 2) * 32 + b], w4.z, acc);
    acc = fmaf(hT[(size_t)(k + 3) * 32 + b], w4.w, acc);
  }
  o[(size_t)b * 1024 + oc] = fmaxf(acc + bias[oc], 0.f);
}

__global__ void __launch_bounds__(256) fc2_kernel(
    const float* __restrict__ h, const float* __restrict__ W,
    const float* __restrict__ bias, float* __restrict__ out)
{
  const int i = blockIdx.x * 256 + threadIdx.x;
  const int b = i >> 5, oo = i & 31;
  const float* wr = W + (size_t)oo * 1024;
  const float* hr = h + (size_t)b * 1024;
  float acc = bias[oo];
  for (int k = 0; k < 1024; k += 4) {
    const float4 w4 = *(const float4*)(wr + k);
    const float4 h4 = *(const float4*)(hr + k);
    acc = fmaf(h4.x, w4.x, acc);
    acc = fmaf(h4.y, w4.y, acc);
    acc = fmaf(h4.z, w4.z, acc);
    acc = fmaf(h4.w, w4.w, acc);
  }
  out[i] = acc;
}

extern "C" void kernel_launch(void* const* d_in, const int* in_sizes, int n_in,
                              void* d_out, int out_size, void* d_ws, size_t ws_size,
                              hipStream_t stream) {
  const float* feats   = (const float*)d_in[0];
  const int*   progs   = (const int*)  d_in[1];
  const float* stem_w1 = (const float*)d_in[2];
  const float* stem_b1 = (const float*)d_in[3];
  const float* stem_w2 = (const float*)d_in[4];
  const float* stem_b2 = (const float*)d_in[5];
  const float* mem_u   = (const float*)d_in[6];
  const float* mem_b   = (const float*)d_in[7];
  const float* cls_w   = (const float*)d_in[8];
  const float* cls_b   = (const float*)d_in[9];
  const float* fc1_w   = (const float*)d_in[10];
  const float* fc1_b   = (const float*)d_in[11];
  const float* fc2_w   = (const float*)d_in[12];
  const float* fc2_b   = (const float*)d_in[13];

  float* ws = (float*)d_ws;
  const size_t F = (size_t)32 * FSZ;
  float* feat  = ws;
  float* outb  = ws + 1 * F;
  float* saved = ws + 2 * F;
  float* h1    = ws + 3 * F;
  float* h2    = ws + 4 * F;
  float* hT    = ws + 5 * F;
  float* fc1o  = ws + 6 * F;                 // 32768 floats
  int*   ctr   = (int*)(ws + 6 * F + 40960); // 32 b x 32-int lines

  hipMemsetAsync(ctr, 0, 32 * 32 * sizeof(int), stream);

  persist_kernel<<<dim3(512), dim3(256), 0, stream>>>(
      feats, progs, stem_w1, stem_b1, stem_w2, stem_b2, mem_u, mem_b,
      feat, outb, saved, h1, h2, ctr);

  float* hB = h1; // free after persist
  cls_pool_kernel<<<dim3(8, 32), dim3(256), 0, stream>>>(outb, cls_w, cls_b, hB);
  transpose_kernel<<<dim3(98), dim3(256), 0, stream>>>(hB, hT);
  fc1_kernel<<<dim3(128), dim3(256), 0, stream>>>(hT, fc1_w, fc1_b, fc1o);
  fc2_kernel<<<dim3(4), dim3(256), 0, stream>>>(fc1o, fc2_w, fc2_b, (float*)d_out);
}

// Round 3
// 9258.959 us; speedup vs baseline: 4.4208x; 1.6596x over previous
//
#include <hip/hip_runtime.h>

// Program-guided CNN executor — split-bf16 MFMA persistent version.
// B=32, T=30, C=128, 14x14 (P=196). One WG (512 thr, 8 waves) per batch
// element runs stem + all 30 scan steps on one CU; only __syncthreads.
// Conv = implicit GEMM over 9 taps: D[oc][pos] += W[oc][ic,tap] X[ic][pos+off].
// fp32 emulated as 3 bf16 MFMAs: WhXh + WhXl + WlXh (rel err ~2^-17/conv).
// mfma_f32_32x32x16_bf16: A[m=lane&31][k=(lane>>5)*8+j], B[k][n=lane&31],
// D col=lane&31, row=(reg&3)+8*(reg>>2)+4*(lane>>5)   [m74/m101/m120].

#define NSTEP 30
#define CD 147456            // 128*128*9
#define P 196
#define FSZ 25088            // 128*196 floats per (b, buffer)
#define LROW 18              // LDS row: 16 packed u32 (hi|lo) + 2 pad (2-way only, 8B-aligned)
#define LBUF (272*LROW)

typedef __attribute__((ext_vector_type(8))) short short8;
typedef __attribute__((ext_vector_type(16))) float f32x16;

__constant__ int KIND_TBL[44] = {
  0,0,0,0,1,3,3,3,3,3, 2,2,2,2,2,2,2,2,2,2,
  2,2,2,2,2,2,3,3,3,2, 2,2,2,2,2,2,2,2,2,2, 2,2,3,2};
__constant__ int MIDX_TBL[44] = {
  0,0,0,0,0,0,1,2,3,4, 1,2,3,4,5,6,7,8,9,10,
  11,12,13,14,15,16,5,6,7,17, 18,19,20,21,22,23,24,25,26,27, 28,29,8,30};

__device__ __forceinline__ uint32_t bf16_rne(float x) {
  uint32_t u = __float_as_uint(x);
  return (u + 0x7fffu + ((u >> 16) & 1u)) >> 16;
}
__device__ __forceinline__ uint32_t pack_hl(float x) {
  uint32_t h = bf16_rne(x);
  float rest = x - __uint_as_float(h << 16);
  uint32_t l = bf16_rne(rest);
  return (h << 16) | l;
}
__device__ __forceinline__ float ld_sc0(const float* p) {  // L1-bypass (intra-WG RAW via L2)
  return __hip_atomic_load(p, __ATOMIC_RELAXED, __HIP_MEMORY_SCOPE_AGENT);
}

// Weight repack: fp32 W[oc][ic][tap] -> per (global chunk C, tap) 8KB block:
// [mt(4)][hl(2)][lane(64)][bf16x8], lane=(oc%32)|((ic8)<<5), coalesced frag loads.
// Chunk map: stem1 C 0..63 | stem2 64..71 | unary 72+u*16+conv*8+lc |
//            binary 568+j*32 (conv1 lc0-15, conv2 16-23, conv3 24-31).
__global__ void __launch_bounds__(256) repack_kernel(
    const float* __restrict__ sw1, const float* __restrict__ sw2,
    const float* __restrict__ mu, const float* __restrict__ mb,
    uint32_t* __restrict__ Wp)
{
  const int blk = blockIdx.x;
  const int C = blk / 9, tap = blk % 9;
  const float* src; int nic, lc;
  if (C < 64)       { src = sw1; nic = 1024; lc = C; }
  else if (C < 72)  { src = sw2; nic = 128;  lc = C - 64; }
  else if (C < 568) { int u = (C - 72) >> 4, r = (C - 72) & 15;
                      src = mu + (size_t)u * 2 * CD + (size_t)(r >> 3) * CD;
                      nic = 128; lc = r & 7; }
  else              { int j = (C - 568) >> 5, r = (C - 568) & 31;
                      const float* base = mb + (size_t)j * 4 * CD;
                      if (r < 16)      { src = base;                     nic = 256; lc = r; }
                      else if (r < 24) { src = base + 2 * (size_t)CD;    nic = 128; lc = r - 16; }
                      else             { src = base + 3 * (size_t)CD;    nic = 128; lc = r - 24; } }
  const int mt = threadIdx.x >> 6, lane = threadIdx.x & 63;
  const int oc = mt * 32 + (lane & 31);
  const int ic0 = lc * 16 + (lane >> 5) * 8;
  uint32_t hw[4], lw[4];
#pragma unroll
  for (int pr = 0; pr < 4; ++pr) {
    uint32_t hh[2], ll[2];
#pragma unroll
    for (int e = 0; e < 2; ++e) {
      float x = src[((size_t)oc * nic + (ic0 + pr * 2 + e)) * 9 + tap];
      uint32_t h = bf16_rne(x);
      float rest = x - __uint_as_float(h << 16);
      hh[e] = h; ll[e] = bf16_rne(rest);
    }
    hw[pr] = hh[0] | (hh[1] << 16);
    lw[pr] = ll[0] | (ll[1] << 16);
  }
  uint32_t* dstb = Wp + (size_t)blk * 2048;
  *(uint4*)(dstb + (mt * 2 + 0) * 256 + lane * 4) = make_uint4(hw[0], hw[1], hw[2], hw[3]);
  *(uint4*)(dstb + (mt * 2 + 1) * 256 + lane * 4) = make_uint4(lw[0], lw[1], lw[2], lw[3]);
}

union BU { uint32_t u[4]; uint4 v; short8 s8; };

// One conv3x3 (nic = nc*16 input ch, 128 out ch) for one b, whole WG.
// Waves 0..6 compute row-pairs (oy = 2w, 2w+1); all 8 waves stage.
__device__ __forceinline__ void conv_run(
    uint32_t sbuf[2][LBUF],
    const float* __restrict__ in0, const float* __restrict__ in1, int split, int nc, int C0,
    const uint32_t* __restrict__ Wp, const float* __restrict__ bias,
    float* __restrict__ dst, float* __restrict__ dst2, float* __restrict__ zb,
    const int* imgoff)
{
  const int TAPOFF[9] = {0, 1, 2, 16, 17, 18, 32, 33, 34};
  const int tid = threadIdx.x;
  const int w = tid >> 6, lane = tid & 63, l31 = lane & 31, kq = lane >> 5;
  const int ic16 = tid >> 5;      // 0..15: staged input channel within chunk
  const int pl = tid & 31;

  f32x16 acc[4];
#pragma unroll
  for (int mt = 0; mt < 4; ++mt)
#pragma unroll
    for (int i = 0; i < 16; ++i) acc[mt][i] = 0.f;

  // stage chunk 0
  {
    const float* src = (0 < split) ? in0 + (size_t)ic16 * P : in1 + (size_t)ic16 * P;
#pragma unroll
    for (int i = 0; i < 9; ++i) {
      int p = pl + 32 * i;
      if (p < 272) {
        int off = imgoff[i];
        float x = (off >= 0) ? ld_sc0(src + off) : 0.f;
        sbuf[0][p * LROW + ic16] = pack_hl(x);
      }
    }
  }
  __syncthreads();

  for (int c = 0; c < nc; ++c) {
    // prefetch chunk c+1 into regs (overlaps compute)
    float sv[9];
    const bool more = (c + 1 < nc);
    if (more) {
      int cn = c + 1;
      const float* src = (cn < split) ? in0 + (size_t)(cn * 16 + ic16) * P
                                      : in1 + (size_t)((cn - split) * 16 + ic16) * P;
#pragma unroll
      for (int i = 0; i < 9; ++i) {
        int off = imgoff[i];
        sv[i] = (off >= 0) ? ld_sc0(src + off) : 0.f;
      }
    }
    if (w < 7) {
      const uint32_t* sb = &sbuf[c & 1][0];
      const uint32_t* wtb = Wp + ((size_t)(C0 + c) * 9) * 2048 + lane * 4;
#pragma unroll
      for (int tap = 0; tap < 9; ++tap) {
        const uint32_t* wt = wtb + tap * 2048;
        BU AH[4], AL[4];
#pragma unroll
        for (int mt = 0; mt < 4; ++mt) {
          AH[mt].v = *(const uint4*)(wt + (mt * 2 + 0) * 256);
          AL[mt].v = *(const uint4*)(wt + (mt * 2 + 1) * 256);
        }
        const int pw = (32 * w + l31 + TAPOFF[tap]) * LROW + kq * 8;
        uint2 q0 = *(const uint2*)(sb + pw);
        uint2 q1 = *(const uint2*)(sb + pw + 2);
        uint2 q2 = *(const uint2*)(sb + pw + 4);
        uint2 q3 = *(const uint2*)(sb + pw + 6);
        BU Bh, Bl;
        Bh.u[0] = __builtin_amdgcn_perm(q0.y, q0.x, 0x07060302u);
        Bh.u[1] = __builtin_amdgcn_perm(q1.y, q1.x, 0x07060302u);
        Bh.u[2] = __builtin_amdgcn_perm(q2.y, q2.x, 0x07060302u);
        Bh.u[3] = __builtin_amdgcn_perm(q3.y, q3.x, 0x07060302u);
        Bl.u[0] = __builtin_amdgcn_perm(q0.y, q0.x, 0x05040100u);
        Bl.u[1] = __builtin_amdgcn_perm(q1.y, q1.x, 0x05040100u);
        Bl.u[2] = __builtin_amdgcn_perm(q2.y, q2.x, 0x05040100u);
        Bl.u[3] = __builtin_amdgcn_perm(q3.y, q3.x, 0x05040100u);
#pragma unroll
        for (int mt = 0; mt < 4; ++mt)
          acc[mt] = __builtin_amdgcn_mfma_f32_32x32x16_bf16(AH[mt].s8, Bh.s8, acc[mt], 0, 0, 0);
#pragma unroll
        for (int mt = 0; mt < 4; ++mt)
          acc[mt] = __builtin_amdgcn_mfma_f32_32x32x16_bf16(AH[mt].s8, Bl.s8, acc[mt], 0, 0, 0);
#pragma unroll
        for (int mt = 0; mt < 4; ++mt)
          acc[mt] = __builtin_amdgcn_mfma_f32_32x32x16_bf16(AL[mt].s8, Bh.s8, acc[mt], 0, 0, 0);
      }
    }
    if (more) {
#pragma unroll
      for (int i = 0; i < 9; ++i) {
        int p = pl + 32 * i;
        if (p < 272) sbuf[(c + 1) & 1][p * LROW + ic16] = pack_hl(sv[i]);
      }
    }
    __syncthreads();
  }

  // epilogue: bias (+relu) and store fp32
  if (w < 7) {
    const int ox = l31 & 15, oy = 2 * w + (l31 >> 4);
    if (ox < 14) {
#pragma unroll
      for (int mt = 0; mt < 4; ++mt)
#pragma unroll
        for (int reg = 0; reg < 16; ++reg) {
          int row = (reg & 3) + 8 * (reg >> 2) + 4 * kq;
          int oc = mt * 32 + row;
          float v = acc[mt][reg];
          if (bias) v += bias[oc];
          v = fmaxf(v, 0.f);
          dst[(size_t)oc * P + oy * 14 + ox] = v;
          if (dst2) dst2[(size_t)oc * P + oy * 14 + ox] = v;
          if (zb)   zb[(size_t)oc * P + oy * 14 + ox] = 0.f;
        }
    }
  }
  __syncthreads();  // epilogue stores visible before next conv stages
}

__global__ void __launch_bounds__(512, 2) persist_kernel(
    const float* __restrict__ feats, const int* __restrict__ progs,
    const float* __restrict__ sb1, const float* __restrict__ sb2,
    const uint32_t* __restrict__ Wp,
    float* __restrict__ feat, float* __restrict__ outb, float* __restrict__ saved,
    float* __restrict__ h1, float* __restrict__ h2)
{
  __shared__ uint32_t s_act[2][LBUF];
  const int tid = threadIdx.x;
  const int b = blockIdx.x;
  const size_t bo = (size_t)b * FSZ;

  int imgoff[9];
#pragma unroll
  for (int i = 0; i < 9; ++i) {
    int p = (tid & 31) + 32 * i;
    int row = p >> 4, col = p & 15;
    imgoff[i] = (p < 272 && row >= 1 && row <= 14 && col >= 1 && col <= 14)
                ? (row - 1) * 14 + (col - 1) : -1;
  }

  // stem
  conv_run(s_act, feats + (size_t)b * 1024 * P, nullptr, 1 << 28, 64, 0,  Wp, sb1,
           h1 + bo, nullptr, nullptr, imgoff);
  conv_run(s_act, h1 + bo, nullptr, 1 << 28, 8, 64, Wp, sb2,
           feat + bo, outb + bo, saved + bo, imgoff);

  for (int s = 0; s < NSTEP; ++s) {
    int tok = progs[b * NSTEP + (NSTEP - 1 - s)];
    int kind = KIND_TBL[tok], mi = MIDX_TBL[tok];
    if (kind == 0) continue;
    if (kind == 1) {                 // scene: saved <- out; out <- unary0(feat)
      for (int i = tid; i < FSZ; i += 512)
        saved[bo + i] = ld_sc0(&outb[bo + i]);
      int C0 = 72 + mi * 16;
      conv_run(s_act, feat + bo, nullptr, 1 << 28, 8, C0,     Wp, nullptr, h1 + bo, nullptr, nullptr, imgoff);
      conv_run(s_act, h1 + bo,  nullptr, 1 << 28, 8, C0 + 8, Wp, nullptr, outb + bo, nullptr, nullptr, imgoff);
    } else if (kind == 2) {          // unary
      int C0 = 72 + mi * 16;
      conv_run(s_act, outb + bo, nullptr, 1 << 28, 8, C0,     Wp, nullptr, h1 + bo, nullptr, nullptr, imgoff);
      conv_run(s_act, h1 + bo,  nullptr, 1 << 28, 8, C0 + 8, Wp, nullptr, outb + bo, nullptr, nullptr, imgoff);
    } else {                         // binary: conv1 on concat(out, saved)
      int C0 = 568 + mi * 32;
      conv_run(s_act, outb + bo, saved + bo, 8, 16, C0,      Wp, nullptr, h1 + bo, nullptr, nullptr, imgoff);
      conv_run(s_act, h1 + bo,  nullptr, 1 << 28, 8, C0 + 16, Wp, nullptr, h2 + bo, nullptr, nullptr, imgoff);
      conv_run(s_act, h2 + bo,  nullptr, 1 << 28, 8, C0 + 24, Wp, nullptr, outb + bo, nullptr, nullptr, imgoff);
    }
  }
}

// ---- tail (unchanged from round 2) ----
__global__ void __launch_bounds__(256) cls_pool_kernel(
    const float* __restrict__ x, const float* __restrict__ Wc,
    const float* __restrict__ bc, float* __restrict__ hB)
{
  const int b = blockIdx.y, og = blockIdx.x;
  const int oc0 = og * 64;
  __shared__ float s[16 * P];
  const float* xb = x + (size_t)b * FSZ;
  const int tid = threadIdx.x;
  float acc[13][4];
#pragma unroll
  for (int k = 0; k < 13; ++k) { acc[k][0] = acc[k][1] = acc[k][2] = acc[k][3] = 0.f; }
  for (int c0 = 0; c0 < 128; c0 += 16) {
    __syncthreads();
    for (int i = tid; i < 16 * P; i += 256) s[i] = xb[(size_t)c0 * P + i];
    __syncthreads();
#pragma unroll
    for (int k = 0; k < 13; ++k) {
      const int idx = k * 256 + tid;
      if (idx < 64 * 49) {
        const int oc = oc0 + idx / 49, pp = idx % 49;
        const int py = pp / 7, px = pp % 7;
        const int b0 = 2 * py * 14 + 2 * px, b1 = b0 + 14;
        const float* wr = Wc + (size_t)oc * 128 + c0;
#pragma unroll
        for (int ic = 0; ic < 16; ++ic) {
          const float w = wr[ic];
          const float* sp = s + ic * P;
          const float2 r0 = *(const float2*)(sp + b0);
          const float2 r1 = *(const float2*)(sp + b1);
          acc[k][0] = fmaf(w, r0.x, acc[k][0]);
          acc[k][1] = fmaf(w, r0.y, acc[k][1]);
          acc[k][2] = fmaf(w, r1.x, acc[k][2]);
          acc[k][3] = fmaf(w, r1.y, acc[k][3]);
        }
      }
    }
  }
#pragma unroll
  for (int k = 0; k < 13; ++k) {
    const int idx = k * 256 + tid;
    if (idx < 64 * 49) {
      const int oc = oc0 + idx / 49, pp = idx % 49;
      const float m = fmaxf(fmaxf(acc[k][0], acc[k][1]), fmaxf(acc[k][2], acc[k][3]));
      hB[(size_t)b * 25088 + (size_t)oc * 49 + pp] = fmaxf(m + bc[oc], 0.f);
    }
  }
}

__global__ void __launch_bounds__(256) transpose_kernel(
    const float* __restrict__ hB, float* __restrict__ hT)
{
  __shared__ float t[256 * 33];
  const int k0 = blockIdx.x * 256;
  const int tid = threadIdx.x;
  for (int b = 0; b < 32; ++b)
    t[tid * 33 + b] = hB[(size_t)b * 25088 + k0 + tid];
  __syncthreads();
  for (int i = tid; i < 256 * 32; i += 256) {
    const int k = i >> 5, b = i & 31;
    hT[(size_t)(k0 + k) * 32 + b] = t[k * 33 + b];
  }
}

__global__ void __launch_bounds__(256) fc1_kernel(
    const float* __restrict__ hT, const float* __restrict__ W,
    const float* __restrict__ bias, float* __restrict__ o)
{
  const int b = threadIdx.x & 31, j = threadIdx.x >> 5;
  const int oc = blockIdx.x * 8 + j;
  const float* wr = W + (size_t)oc * 25088;
  float acc = 0.f;
  for (int k = 0; k < 25088; k += 4) {
    const float4 w4 = *(const float4*)(wr + k);
    acc = fmaf(hT[(size_t)(k + 0) * 32 + b], w4.x, acc);
    acc = fmaf(hT[(size_t)(k + 1) * 32 + b], w4.y, acc);
    acc = fmaf(hT[(size_t)(k + 2) * 32 + b], w4.z, acc);
    acc = fmaf(hT[(size_t)(k + 3) * 32 + b], w4.w, acc);
  }
  o[(size_t)b * 1024 + oc] = fmaxf(acc + bias[oc], 0.f);
}

__global__ void __launch_bounds__(256) fc2_kernel(
    const float* __restrict__ h, const float* __restrict__ W,
    const float* __restrict__ bias, float* __restrict__ out)
{
  const int i = blockIdx.x * 256 + threadIdx.x;
  const int b = i >> 5, oo = i & 31;
  const float* wr = W + (size_t)oo * 1024;
  const float* hr = h + (size_t)b * 1024;
  float acc = bias[oo];
  for (int k = 0; k < 1024; k += 4) {
    const float4 w4 = *(const float4*)(wr + k);
    const float4 h4 = *(const float4*)(hr + k);
    acc = fmaf(h4.x, w4.x, acc);
    acc = fmaf(h4.y, w4.y, acc);
    acc = fmaf(h4.z, w4.z, acc);
    acc = fmaf(h4.w, w4.w, acc);
  }
  out[i] = acc;
}

extern "C" void kernel_launch(void* const* d_in, const int* in_sizes, int n_in,
                              void* d_out, int out_size, void* d_ws, size_t ws_size,
                              hipStream_t stream) {
  const float* feats   = (const float*)d_in[0];
  const int*   progs   = (const int*)  d_in[1];
  const float* stem_w1 = (const float*)d_in[2];
  const float* stem_b1 = (const float*)d_in[3];
  const float* stem_w2 = (const float*)d_in[4];
  const float* stem_b2 = (const float*)d_in[5];
  const float* mem_u   = (const float*)d_in[6];
  const float* mem_b   = (const float*)d_in[7];
  const float* cls_w   = (const float*)d_in[8];
  const float* cls_b   = (const float*)d_in[9];
  const float* fc1_w   = (const float*)d_in[10];
  const float* fc1_b   = (const float*)d_in[11];
  const float* fc2_w   = (const float*)d_in[12];
  const float* fc2_b   = (const float*)d_in[13];

  float* ws = (float*)d_ws;
  const size_t F = (size_t)32 * FSZ;
  float*    feat  = ws;
  float*    outb  = ws + 1 * F;
  float*    saved = ws + 2 * F;
  float*    h1    = ws + 3 * F;
  float*    h2    = ws + 4 * F;
  uint32_t* Wp    = (uint32_t*)(ws + 5 * F);   // 7704 blocks x 8KB = 63.1 MB

  repack_kernel<<<dim3(7704), dim3(256), 0, stream>>>(stem_w1, stem_w2, mem_u, mem_b, Wp);

  persist_kernel<<<dim3(32), dim3(512), 0, stream>>>(
      feats, progs, stem_b1, stem_b2, Wp, feat, outb, saved, h1, h2);

  float* hB   = h1;     // free after persist
  float* hT   = h2;
  float* fc1o = saved;
  cls_pool_kernel<<<dim3(8, 32), dim3(256), 0, stream>>>(outb, cls_w, cls_b, hB);
  transpose_kernel<<<dim3(98), dim3(256), 0, stream>>>(hB, hT);
  fc1_kernel<<<dim3(128), dim3(256), 0, stream>>>(hT, fc1_w, fc1_b, fc1o);
  fc2_kernel<<<dim3(4), dim3(256), 0, stream>>>(fc1o, fc2_w, fc2_b, (float*)d_out);
}

// Round 4
// 3349.802 us; speedup vs baseline: 12.2192x; 2.7640x over previous
//
#include <hip/hip_runtime.h>

// Program-guided CNN executor — split-bf16 MFMA, oc-split persistent version.
// B=32, T=30, C=128, 14x14 (P=196). 128 WGs = 32 b x 4 oc-tiles (mt). Each WG
// (512 thr, 8 waves) computes a 32-oc slice; the 4 WGs of one b sync between
// conv stages via monotone atomic barriers (4 arrivals, agent scope).
// Conv = implicit GEMM over 9 taps; fp32 = WhXh + WhXl + WlXh (3x bf16 MFMA).
// Next chunk's weights are prefetched into explicit double-buffered register
// sets so global loads issue a full chunk ahead of consumption.

#define NSTEP 30
#define CD 147456            // 128*128*9
#define P 196
#define FSZ 25088            // 128*196 floats per (b, buffer)
#define LROW 18              // LDS row: 16 packed u32 (hi|lo) + 2 pad
#define LBUF (272*LROW)

typedef __attribute__((ext_vector_type(8))) short short8;
typedef __attribute__((ext_vector_type(16))) float f32x16;

__constant__ int KIND_TBL[44] = {
  0,0,0,0,1,3,3,3,3,3, 2,2,2,2,2,2,2,2,2,2,
  2,2,2,2,2,2,3,3,3,2, 2,2,2,2,2,2,2,2,2,2, 2,2,3,2};
__constant__ int MIDX_TBL[44] = {
  0,0,0,0,0,0,1,2,3,4, 1,2,3,4,5,6,7,8,9,10,
  11,12,13,14,15,16,5,6,7,17, 18,19,20,21,22,23,24,25,26,27, 28,29,8,30};

__device__ __forceinline__ uint32_t bf16_rne(float x) {
  uint32_t u = __float_as_uint(x);
  return (u + 0x7fffu + ((u >> 16) & 1u)) >> 16;
}
__device__ __forceinline__ uint32_t pack_hl(float x) {
  uint32_t h = bf16_rne(x);
  float rest = x - __uint_as_float(h << 16);
  uint32_t l = bf16_rne(rest);
  return (h << 16) | l;
}
__device__ __forceinline__ float ld_sc0(const float* p) {  // L1-bypass agent load
  return __hip_atomic_load(p, __ATOMIC_RELAXED, __HIP_MEMORY_SCOPE_AGENT);
}

// Per-b barrier among the 4 WGs of one batch element (monotone counter).
__device__ __forceinline__ void bbar(int* __restrict__ ctr, int target) {
  __syncthreads();
  if (threadIdx.x == 0) {
    __hip_atomic_fetch_add(ctr, 1, __ATOMIC_RELEASE, __HIP_MEMORY_SCOPE_AGENT);
    while (__hip_atomic_load(ctr, __ATOMIC_ACQUIRE, __HIP_MEMORY_SCOPE_AGENT) < target)
      __builtin_amdgcn_s_sleep(2);
  }
  __syncthreads();
}

// Weight repack (unchanged layout): per (chunk C, tap) 8KB block:
// [mt(4)][hl(2)][lane(64)][bf16x8]. lane=(oc%32)|((ic8)<<5).
__global__ void __launch_bounds__(256) repack_kernel(
    const float* __restrict__ sw1, const float* __restrict__ sw2,
    const float* __restrict__ mu, const float* __restrict__ mb,
    uint32_t* __restrict__ Wp)
{
  const int blk = blockIdx.x;
  const int C = blk / 9, tap = blk % 9;
  const float* src; int nic, lc;
  if (C < 64)       { src = sw1; nic = 1024; lc = C; }
  else if (C < 72)  { src = sw2; nic = 128;  lc = C - 64; }
  else if (C < 568) { int u = (C - 72) >> 4, r = (C - 72) & 15;
                      src = mu + (size_t)u * 2 * CD + (size_t)(r >> 3) * CD;
                      nic = 128; lc = r & 7; }
  else              { int j = (C - 568) >> 5, r = (C - 568) & 31;
                      const float* base = mb + (size_t)j * 4 * CD;
                      if (r < 16)      { src = base;                  nic = 256; lc = r; }
                      else if (r < 24) { src = base + 2 * (size_t)CD; nic = 128; lc = r - 16; }
                      else             { src = base + 3 * (size_t)CD; nic = 128; lc = r - 24; } }
  const int mt = threadIdx.x >> 6, lane = threadIdx.x & 63;
  const int oc = mt * 32 + (lane & 31);
  const int ic0 = lc * 16 + (lane >> 5) * 8;
  uint32_t hw[4], lw[4];
#pragma unroll
  for (int pr = 0; pr < 4; ++pr) {
    uint32_t hh[2], ll[2];
#pragma unroll
    for (int e = 0; e < 2; ++e) {
      float x = src[((size_t)oc * nic + (ic0 + pr * 2 + e)) * 9 + tap];
      uint32_t h = bf16_rne(x);
      float rest = x - __uint_as_float(h << 16);
      hh[e] = h; ll[e] = bf16_rne(rest);
    }
    hw[pr] = hh[0] | (hh[1] << 16);
    lw[pr] = ll[0] | (ll[1] << 16);
  }
  uint32_t* dstb = Wp + (size_t)blk * 2048;
  *(uint4*)(dstb + (mt * 2 + 0) * 256 + lane * 4) = make_uint4(hw[0], hw[1], hw[2], hw[3]);
  *(uint4*)(dstb + (mt * 2 + 1) * 256 + lane * 4) = make_uint4(lw[0], lw[1], lw[2], lw[3]);
}

union BU { uint32_t u[4]; uint4 v; short8 s8; };

__device__ __forceinline__ void load_wchunk(const uint32_t* __restrict__ wb,
                                            BU* wh, BU* wl) {
#pragma unroll
  for (int t = 0; t < 9; ++t) {
    wh[t].v = *(const uint4*)(wb + t * 2048);
    wl[t].v = *(const uint4*)(wb + t * 2048 + 256);
  }
}

__device__ __forceinline__ void mfma_chunk(const uint32_t* __restrict__ sb,
                                           int pwbase, const BU* wh, const BU* wl,
                                           f32x16& acc) {
  const int TAPOFF[9] = {0, 1, 2, 16, 17, 18, 32, 33, 34};
#pragma unroll
  for (int tap = 0; tap < 9; ++tap) {
    const int pw = pwbase + TAPOFF[tap] * LROW;
    uint2 q0 = *(const uint2*)(sb + pw);
    uint2 q1 = *(const uint2*)(sb + pw + 2);
    uint2 q2 = *(const uint2*)(sb + pw + 4);
    uint2 q3 = *(const uint2*)(sb + pw + 6);
    BU Bh, Bl;
    Bh.u[0] = __builtin_amdgcn_perm(q0.y, q0.x, 0x07060302u);
    Bh.u[1] = __builtin_amdgcn_perm(q1.y, q1.x, 0x07060302u);
    Bh.u[2] = __builtin_amdgcn_perm(q2.y, q2.x, 0x07060302u);
    Bh.u[3] = __builtin_amdgcn_perm(q3.y, q3.x, 0x07060302u);
    Bl.u[0] = __builtin_amdgcn_perm(q0.y, q0.x, 0x05040100u);
    Bl.u[1] = __builtin_amdgcn_perm(q1.y, q1.x, 0x05040100u);
    Bl.u[2] = __builtin_amdgcn_perm(q2.y, q2.x, 0x05040100u);
    Bl.u[3] = __builtin_amdgcn_perm(q3.y, q3.x, 0x05040100u);
    acc = __builtin_amdgcn_mfma_f32_32x32x16_bf16(wh[tap].s8, Bh.s8, acc, 0, 0, 0);
    acc = __builtin_amdgcn_mfma_f32_32x32x16_bf16(wh[tap].s8, Bl.s8, acc, 0, 0, 0);
    acc = __builtin_amdgcn_mfma_f32_32x32x16_bf16(wl[tap].s8, Bh.s8, acc, 0, 0, 0);
  }
}

// One conv3x3 (nc*16 input ch, this WG's 32-oc slice mt) for one b.
__device__ __forceinline__ void conv_run(
    uint32_t sbuf[2][LBUF],
    const float* __restrict__ in0, const float* __restrict__ in1, int split, int nc,
    int C0, int mt,
    const uint32_t* __restrict__ Wp, const float* __restrict__ bias,
    float* __restrict__ dst, float* __restrict__ dst2, float* __restrict__ zb,
    const int* imgoff)
{
  const int tid = threadIdx.x;
  const int w = tid >> 6, lane = tid & 63, l31 = lane & 31, kq = lane >> 5;
  const int ic16 = tid >> 5, pl = tid & 31;
  const int pwbase = (32 * w + l31) * LROW + kq * 8;
  const bool cw = (w < 7);
  const uint32_t* wbase = Wp + (size_t)C0 * 9 * 2048 + (mt * 2) * 256 + lane * 4;

  f32x16 acc;
#pragma unroll
  for (int i = 0; i < 16; ++i) acc[i] = 0.f;

  BU whA[9], wlA[9], whB[9], wlB[9];
  if (cw) load_wchunk(wbase, whA, wlA);
  { // stage chunk 0
    const float* src = in0 + (size_t)ic16 * P;
#pragma unroll
    for (int i = 0; i < 9; ++i) {
      int p = pl + 32 * i;
      if (p < 272) {
        int off = imgoff[i];
        float x = (off >= 0) ? ld_sc0(src + off) : 0.f;
        sbuf[0][p * LROW + ic16] = pack_hl(x);
      }
    }
  }
  __syncthreads();

  int c = 0;
  while (true) {
    { // even chunk: consume A, prefetch into B
      const bool more = c + 1 < nc;
      float sv[9];
      if (more) {
        const int cn = c + 1;
        const float* src = (cn < split) ? in0 + (size_t)(cn * 16 + ic16) * P
                                        : in1 + (size_t)((cn - split) * 16 + ic16) * P;
#pragma unroll
        for (int i = 0; i < 9; ++i) {
          int off = imgoff[i];
          sv[i] = (off >= 0) ? ld_sc0(src + off) : 0.f;
        }
        if (cw) load_wchunk(wbase + (size_t)(c + 1) * 9 * 2048, whB, wlB);
      }
      if (cw) mfma_chunk(&sbuf[c & 1][0], pwbase, whA, wlA, acc);
      if (more) {
#pragma unroll
        for (int i = 0; i < 9; ++i) {
          int p = pl + 32 * i;
          if (p < 272) sbuf[(c + 1) & 1][p * LROW + ic16] = pack_hl(sv[i]);
        }
      }
      __syncthreads();
      if (++c >= nc) break;
    }
    { // odd chunk: consume B, prefetch into A
      const bool more = c + 1 < nc;
      float sv[9];
      if (more) {
        const int cn = c + 1;
        const float* src = (cn < split) ? in0 + (size_t)(cn * 16 + ic16) * P
                                        : in1 + (size_t)((cn - split) * 16 + ic16) * P;
#pragma unroll
        for (int i = 0; i < 9; ++i) {
          int off = imgoff[i];
          sv[i] = (off >= 0) ? ld_sc0(src + off) : 0.f;
        }
        if (cw) load_wchunk(wbase + (size_t)(c + 1) * 9 * 2048, whA, wlA);
      }
      if (cw) mfma_chunk(&sbuf[c & 1][0], pwbase, whB, wlB, acc);
      if (more) {
#pragma unroll
        for (int i = 0; i < 9; ++i) {
          int p = pl + 32 * i;
          if (p < 272) sbuf[(c + 1) & 1][p * LROW + ic16] = pack_hl(sv[i]);
        }
      }
      __syncthreads();
      if (++c >= nc) break;
    }
  }

  if (cw) {
    const int ox = l31 & 15, oy = 2 * w + (l31 >> 4);
    if (ox < 14) {
#pragma unroll
      for (int reg = 0; reg < 16; ++reg) {
        int row = (reg & 3) + 8 * (reg >> 2) + 4 * kq;
        int oc = mt * 32 + row;
        float v = acc[reg];
        if (bias) v += bias[row];
        v = fmaxf(v, 0.f);
        dst[(size_t)oc * P + oy * 14 + ox] = v;
        if (dst2) dst2[(size_t)oc * P + oy * 14 + ox] = v;
        if (zb)   zb[(size_t)oc * P + oy * 14 + ox] = 0.f;
      }
    }
  }
}

__global__ void __launch_bounds__(512, 2) persist_kernel(
    const float* __restrict__ feats, const int* __restrict__ progs,
    const float* __restrict__ sb1, const float* __restrict__ sb2,
    const uint32_t* __restrict__ Wp,
    float* __restrict__ feat, float* __restrict__ outb, float* __restrict__ saved,
    float* __restrict__ h1, float* __restrict__ h2, int* __restrict__ ctr)
{
  __shared__ uint32_t s_act[2][LBUF];
  const int tid = threadIdx.x;
  const int b = blockIdx.x >> 2;
  const int mt = blockIdx.x & 3;
  const size_t bo = (size_t)b * FSZ;
  int* myctr = ctr + b * 32;
  int phase = 0;

  int imgoff[9];
#pragma unroll
  for (int i = 0; i < 9; ++i) {
    int p = (tid & 31) + 32 * i;
    int row = p >> 4, col = p & 15;
    imgoff[i] = (p < 272 && row >= 1 && row <= 14 && col >= 1 && col <= 14)
                ? (row - 1) * 14 + (col - 1) : -1;
  }

  conv_run(s_act, feats + (size_t)b * 1024 * P, nullptr, 1 << 28, 64, 0, mt, Wp,
           sb1 + mt * 32, h1 + bo, nullptr, nullptr, imgoff);
  bbar(myctr, ++phase * 4);
  conv_run(s_act, h1 + bo, nullptr, 1 << 28, 8, 64, mt, Wp,
           sb2 + mt * 32, feat + bo, outb + bo, saved + bo, imgoff);
  bbar(myctr, ++phase * 4);

  for (int s = 0; s < NSTEP; ++s) {
    int tok = progs[b * NSTEP + (NSTEP - 1 - s)];
    int kind = KIND_TBL[tok], mi = MIDX_TBL[tok];
    if (kind == 0) continue;
    if (kind == 1) {                 // scene: saved <- out (own slice); out <- unary0(feat)
      const size_t so = bo + (size_t)mt * 32 * P;
      for (int i = tid; i < 32 * P; i += 512)
        saved[so + i] = ld_sc0(&outb[so + i]);
      int C0 = 72 + mi * 16;
      conv_run(s_act, feat + bo, nullptr, 1 << 28, 8, C0, mt, Wp, nullptr,
               h1 + bo, nullptr, nullptr, imgoff);
      bbar(myctr, ++phase * 4);
      conv_run(s_act, h1 + bo, nullptr, 1 << 28, 8, C0 + 8, mt, Wp, nullptr,
               outb + bo, nullptr, nullptr, imgoff);
      bbar(myctr, ++phase * 4);
    } else if (kind == 2) {          // unary
      int C0 = 72 + mi * 16;
      conv_run(s_act, outb + bo, nullptr, 1 << 28, 8, C0, mt, Wp, nullptr,
               h1 + bo, nullptr, nullptr, imgoff);
      bbar(myctr, ++phase * 4);
      conv_run(s_act, h1 + bo, nullptr, 1 << 28, 8, C0 + 8, mt, Wp, nullptr,
               outb + bo, nullptr, nullptr, imgoff);
      bbar(myctr, ++phase * 4);
    } else {                         // binary
      int C0 = 568 + mi * 32;
      conv_run(s_act, outb + bo, saved + bo, 8, 16, C0, mt, Wp, nullptr,
               h1 + bo, nullptr, nullptr, imgoff);
      bbar(myctr, ++phase * 4);
      conv_run(s_act, h1 + bo, nullptr, 1 << 28, 8, C0 + 16, mt, Wp, nullptr,
               h2 + bo, nullptr, nullptr, imgoff);
      bbar(myctr, ++phase * 4);
      conv_run(s_act, h2 + bo, nullptr, 1 << 28, 8, C0 + 24, mt, Wp, nullptr,
               outb + bo, nullptr, nullptr, imgoff);
      bbar(myctr, ++phase * 4);
    }
  }
}

// ---- tail ----
__global__ void __launch_bounds__(256) cls_pool_kernel(
    const float* __restrict__ x, const float* __restrict__ Wc,
    const float* __restrict__ bc, float* __restrict__ hB)
{
  const int b = blockIdx.y, og = blockIdx.x;
  const int oc0 = og * 64;
  __shared__ float s[16 * P];
  const float* xb = x + (size_t)b * FSZ;
  const int tid = threadIdx.x;
  float acc[13][4];
#pragma unroll
  for (int k = 0; k < 13; ++k) { acc[k][0] = acc[k][1] = acc[k][2] = acc[k][3] = 0.f; }
  for (int c0 = 0; c0 < 128; c0 += 16) {
    __syncthreads();
    for (int i = tid; i < 16 * P; i += 256) s[i] = xb[(size_t)c0 * P + i];
    __syncthreads();
#pragma unroll
    for (int k = 0; k < 13; ++k) {
      const int idx = k * 256 + tid;
      if (idx < 64 * 49) {
        const int oc = oc0 + idx / 49, pp = idx % 49;
        const int py = pp / 7, px = pp % 7;
        const int b0 = 2 * py * 14 + 2 * px, b1 = b0 + 14;
        const float* wr = Wc + (size_t)oc * 128 + c0;
#pragma unroll
        for (int ic = 0; ic < 16; ++ic) {
          const float w = wr[ic];
          const float* sp = s + ic * P;
          const float2 r0 = *(const float2*)(sp + b0);
          const float2 r1 = *(const float2*)(sp + b1);
          acc[k][0] = fmaf(w, r0.x, acc[k][0]);
          acc[k][1] = fmaf(w, r0.y, acc[k][1]);
          acc[k][2] = fmaf(w, r1.x, acc[k][2]);
          acc[k][3] = fmaf(w, r1.y, acc[k][3]);
        }
      }
    }
  }
#pragma unroll
  for (int k = 0; k < 13; ++k) {
    const int idx = k * 256 + tid;
    if (idx < 64 * 49) {
      const int oc = oc0 + idx / 49, pp = idx % 49;
      const float m = fmaxf(fmaxf(acc[k][0], acc[k][1]), fmaxf(acc[k][2], acc[k][3]));
      hB[(size_t)b * 25088 + (size_t)oc * 49 + pp] = fmaxf(m + bc[oc], 0.f);
    }
  }
}

__global__ void __launch_bounds__(256) transpose_kernel(
    const float* __restrict__ hB, float* __restrict__ hT)
{
  __shared__ float t[256 * 33];
  const int k0 = blockIdx.x * 256;
  const int tid = threadIdx.x;
  for (int b = 0; b < 32; ++b)
    t[tid * 33 + b] = hB[(size_t)b * 25088 + k0 + tid];
  __syncthreads();
  for (int i = tid; i < 256 * 32; i += 256) {
    const int k = i >> 5, b = i & 31;
    hT[(size_t)(k0 + k) * 32 + b] = t[k * 33 + b];
  }
}

// 256 WGs: 4 oc each, 2-way K split, LDS pair-reduce.
__global__ void __launch_bounds__(256) fc1_kernel(
    const float* __restrict__ hT, const float* __restrict__ W,
    const float* __restrict__ bias, float* __restrict__ o)
{
  const int b = threadIdx.x & 31, j = threadIdx.x >> 5;   // j 0..7
  const int oc = blockIdx.x * 4 + (j & 3);
  const int kh = j >> 2;
  const float* wr = W + (size_t)oc * 25088 + (size_t)kh * 12544;
  const float* ht = hT + (size_t)kh * 12544 * 32;
  float acc = 0.f;
  for (int k = 0; k < 12544; k += 4) {
    const float4 w4 = *(const float4*)(wr + k);
    acc = fmaf(ht[(size_t)(k + 0) * 32 + b], w4.x, acc);
    acc = fmaf(ht[(size_t)(k + 1) * 32 + b], w4.y, acc);
    acc = fmaf(ht[(size_t)(k + 2) * 32 + b], w4.z, acc);
    acc = fmaf(ht[(size_t)(k + 3) * 32 + b], w4.w, acc);
  }
  __shared__ float red[8][32];
  red[j][b] = acc;
  __syncthreads();
  if (j < 4)
    o[(size_t)b * 1024 + oc] = fmaxf(red[j][b] + red[j + 4][b] + bias[oc], 0.f);
}

__global__ void __launch_bounds__(256) fc2_kernel(
    const float* __restrict__ h, const float* __restrict__ W,
    const float* __restrict__ bias, float* __restrict__ out)
{
  const int i = blockIdx.x * 256 + threadIdx.x;
  const int b = i >> 5, oo = i & 31;
  const float* wr = W + (size_t)oo * 1024;
  const float* hr = h + (size_t)b * 1024;
  float acc = bias[oo];
  for (int k = 0; k < 1024; k += 4) {
    const float4 w4 = *(const float4*)(wr + k);
    const float4 h4 = *(const float4*)(hr + k);
    acc = fmaf(h4.x, w4.x, acc);
    acc = fmaf(h4.y, w4.y, acc);
    acc = fmaf(h4.z, w4.z, acc);
    acc = fmaf(h4.w, w4.w, acc);
  }
  out[i] = acc;
}

extern "C" void kernel_launch(void* const* d_in, const int* in_sizes, int n_in,
                              void* d_out, int out_size, void* d_ws, size_t ws_size,
                              hipStream_t stream) {
  const float* feats   = (const float*)d_in[0];
  const int*   progs   = (const int*)  d_in[1];
  const float* stem_w1 = (const float*)d_in[2];
  const float* stem_b1 = (const float*)d_in[3];
  const float* stem_w2 = (const float*)d_in[4];
  const float* stem_b2 = (const float*)d_in[5];
  const float* mem_u   = (const float*)d_in[6];
  const float* mem_b   = (const float*)d_in[7];
  const float* cls_w   = (const float*)d_in[8];
  const float* cls_b   = (const float*)d_in[9];
  const float* fc1_w   = (const float*)d_in[10];
  const float* fc1_b   = (const float*)d_in[11];
  const float* fc2_w   = (const float*)d_in[12];
  const float* fc2_b   = (const float*)d_in[13];

  float* ws = (float*)d_ws;
  const size_t F = (size_t)32 * FSZ;
  float*    feat  = ws;
  float*    outb  = ws + 1 * F;
  float*    saved = ws + 2 * F;
  float*    h1    = ws + 3 * F;
  float*    h2    = ws + 4 * F;
  uint32_t* Wp    = (uint32_t*)(ws + 5 * F);          // 7704 x 8KB = 63.1 MB
  int*      ctr   = (int*)(Wp + (size_t)7704 * 2048); // 32 b x 32-int lines

  hipMemsetAsync(ctr, 0, 32 * 32 * sizeof(int), stream);

  repack_kernel<<<dim3(7704), dim3(256), 0, stream>>>(stem_w1, stem_w2, mem_u, mem_b, Wp);

  persist_kernel<<<dim3(128), dim3(512), 0, stream>>>(
      feats, progs, stem_b1, stem_b2, Wp, feat, outb, saved, h1, h2, ctr);

  float* hB   = h1;
  float* hT   = h2;
  float* fc1o = saved;
  cls_pool_kernel<<<dim3(8, 32), dim3(256), 0, stream>>>(outb, cls_w, cls_b, hB);
  transpose_kernel<<<dim3(98), dim3(256), 0, stream>>>(hB, hT);
  fc1_kernel<<<dim3(256), dim3(256), 0, stream>>>(hT, fc1_w, fc1_b, fc1o);
  fc2_kernel<<<dim3(4), dim3(256), 0, stream>>>(fc1o, fc2_w, fc2_b, (float*)d_out);
}